// Round 7
// baseline (434.484 us; speedup 1.0000x reference)
//
#include <hip/hip_runtime.h>
#include <hip/hip_fp16.h>

#define NRAYS   65536      // B*T*R = 4*2*8192
#define NP      48         // samples per ray
#define NKP     64
#define OSTRIDE 69         // mask(1) + depth(1) + ch(3) + kp(64)
#define NPAIRS  8388608
#define NBUCK   8          // buckets = ray>>13 (8192 rays each)
#define NWAVES  8192       // bin_kernel global waves
#define PAIRS_PER_WAVE 1024
#define SEGCAP  192        // records per (wave,bucket) segment; mean 128 + 6 sigma

// ws layout (64B-aligned regions):
//   [0)        red[2]     : unsigned min/max bits of depths
//   [64)       wflat      : NRAYS*NP fp16 masked weights        (6,291,456 B)
//   [6291520)  cnt        : NWAVES*NBUCK int counts             (  262,144 B)
//   [6553664)  recs       : NWAVES*NBUCK*SEGCAP int2 records    (100,663,296 B)
#define WS_WFLAT_OFF 64
#define WS_CNT_OFF   6291520
#define WS_REC_OFF   6553664
#define WS_NEED      (WS_REC_OFF + (size_t)NWAVES * NBUCK * SEGCAP * 8)

__global__ void init_red(unsigned* __restrict__ red) {
  red[0] = 0x7F800000u;  // +inf bits (min identity for positive floats)
  red[1] = 0u;           // max identity for positive floats
}

// 4 lanes per ray; lane `seg` owns samples [12*seg, 12*seg+12).
// Transmittance is a product recurrence; 3 shfls reconstruct the true prefix.
__global__ __launch_bounds__(256) void composite_kernel(
    const float* __restrict__ shape,
    const float* __restrict__ depths,
    const float* __restrict__ channels,
    const int*   __restrict__ valid,
    float* __restrict__ out,
    unsigned short* __restrict__ wflat,
    unsigned* __restrict__ red)
{
  const int gt   = blockIdx.x * blockDim.x + threadIdx.x;
  const int ray  = gt >> 2;          // 64 rays per 256-thread block
  const int seg  = gt & 3;
  const int lane = threadIdx.x & 63;

  const float4* s4 = reinterpret_cast<const float4*>(shape  + (size_t)ray * NP + seg * 12);
  const float4* d4 = reinterpret_cast<const float4*>(depths + (size_t)ray * NP + seg * 12);
  const int4*   v4 = reinterpret_cast<const int4*>  (valid  + (size_t)ray * NP + seg * 12);
  const float4* c4 = reinterpret_cast<const float4*>(channels + (size_t)ray * NP * 3 + seg * 36);

  float Tl = 1.0f;
  float wt = 0.0f, wd = 0.0f;
  float c0 = 0.0f, c1 = 0.0f, c2 = 0.0f;
  float wm[12];
  float dmin = __int_as_float(0x7F800000);
  float dmax = 0.0f;

#pragma unroll
  for (int c = 0; c < 3; ++c) {
    float4 s = s4[c];
    float4 d = d4[c];
    int4   v = v4[c];
    float4 ca = c4[c * 3 + 0];
    float4 cb = c4[c * 3 + 1];
    float4 cc = c4[c * 3 + 2];
    float sv[4]  = {s.x, s.y, s.z, s.w};
    float dv[4]  = {d.x, d.y, d.z, d.w};
    int   vv[4]  = {v.x, v.y, v.z, v.w};
    float cf[12] = {ca.x, ca.y, ca.z, ca.w, cb.x, cb.y, cb.z, cb.w,
                    cc.x, cc.y, cc.z, cc.w};
#pragma unroll
    for (int j = 0; j < 4; ++j) {
      float a = 1.0f / (1.0f + expf(-sv[j]));   // sigmoid
      float w = a * Tl;
      Tl = Tl * ((1.0f - a) + 1e-10f);          // reference op order
      wt += w;
      wd += w * dv[j];
      float m = vv[j] ? w : 0.0f;
      wm[c * 4 + j] = m;
      c0 += m * cf[3 * j + 0];
      c1 += m * cf[3 * j + 1];
      c2 += m * cf[3 * j + 2];
      dmin = fminf(dmin, dv[j]);
      dmax = fmaxf(dmax, dv[j]);
    }
  }

  // prefix product over the 4-lane group
  const int base = lane & ~3;
  const float P0 = __shfl(Tl, base + 0, 64);
  const float P1 = __shfl(Tl, base + 1, 64);
  const float P2 = __shfl(Tl, base + 2, 64);
  float Tpre = 1.0f;
  if (seg > 0) Tpre *= P0;
  if (seg > 1) Tpre *= P1;
  if (seg > 2) Tpre *= P2;

  wt *= Tpre; wd *= Tpre; c0 *= Tpre; c1 *= Tpre; c2 *= Tpre;
  wt += __shfl_xor(wt, 1, 64); wt += __shfl_xor(wt, 2, 64);
  wd += __shfl_xor(wd, 1, 64); wd += __shfl_xor(wd, 2, 64);
  c0 += __shfl_xor(c0, 1, 64); c0 += __shfl_xor(c0, 2, 64);
  c1 += __shfl_xor(c1, 1, 64); c1 += __shfl_xor(c1, 2, 64);
  c2 += __shfl_xor(c2, 1, 64); c2 += __shfl_xor(c2, 2, 64);

  ushort4* w4o = reinterpret_cast<ushort4*>(wflat + (size_t)ray * NP + seg * 12);
#pragma unroll
  for (int c = 0; c < 3; ++c) {
    ushort4 h;
    h.x = __half_as_ushort(__float2half(Tpre * wm[c * 4 + 0]));
    h.y = __half_as_ushort(__float2half(Tpre * wm[c * 4 + 1]));
    h.z = __half_as_ushort(__float2half(Tpre * wm[c * 4 + 2]));
    h.w = __half_as_ushort(__float2half(Tpre * wm[c * 4 + 3]));
    w4o[c] = h;
  }

  if (seg == 0) {
    const size_t ob = (size_t)ray * OSTRIDE;
    out[ob + 0] = fminf(fmaxf(wt, 0.0f), 1.0f);
    out[ob + 1] = wd / wt;                        // depth (clipped in finalize)
    out[ob + 2] = fminf(fmaxf(c0, 0.0f), 1.0f);
    out[ob + 3] = fminf(fmaxf(c1, 0.0f), 1.0f);
    out[ob + 4] = fminf(fmaxf(c2, 0.0f), 1.0f);
  }

#pragma unroll
  for (int o = 32; o >= 1; o >>= 1) {
    dmin = fminf(dmin, __shfl_xor(dmin, o, 64));
    dmax = fmaxf(dmax, __shfl_xor(dmax, o, 64));
  }
  if (lane == 0) {
    atomicMin(&red[0], __float_as_uint(dmin));
    atomicMax(&red[1], __float_as_uint(dmax));
  }
}

// Pass A: bin pairs by output bucket (ray>>13) into per-(wave,bucket) segments.
// Deterministic wave-segment layout -> no global atomics; LDS cursors only.
__global__ __launch_bounds__(256) void bin_kernel(
    const int*   __restrict__ sidx,
    const int*   __restrict__ kidx,
    const float* __restrict__ kp_w,
    int2* __restrict__ recs,
    int*  __restrict__ cnt)
{
  __shared__ int cur[4][NBUCK];
  const int wid  = threadIdx.x >> 6;
  const int lane = threadIdx.x & 63;
  if (lane < NBUCK) cur[wid][lane] = 0;
  __syncthreads();

  const int gw    = (blockIdx.x * blockDim.x + threadIdx.x) >> 6;  // global wave
  const int pbase = gw * PAIRS_PER_WAVE;

  for (int i = 0; i < PAIRS_PER_WAVE / 64; ++i) {
    const int p = pbase + i * 64 + lane;
    const unsigned s = (unsigned)sidx[p];
    const unsigned k = (unsigned)kidx[p];
    const float    w = kp_w[p];
    const unsigned ray = s / 48u;                 // compiler magic-div
    const unsigned b   = ray >> 13;               // bucket 0..7
    const int pos = atomicAdd(&cur[wid][b], 1);
    if (pos < SEGCAP) {
      int2 r;
      r.x = (int)(s | (k << 22));                 // sidx:22b | kidx:6b
      r.y = __float_as_int(w);
      recs[(size_t)(gw * NBUCK + (int)b) * SEGCAP + pos] = r;
    }
  }
  if (lane < NBUCK) {
    int c = cur[wid][lane];
    cnt[gw * NBUCK + lane] = c < SEGCAP ? c : SEGCAP;
  }
}

// Pass B: bucket k handled by blocks with blockIdx%8==k (XCD round-robin) ->
// wflat slice (786KB) + out slice (2.3MB) stay L2-resident per XCD.
__global__ __launch_bounds__(256) void kp_accum_kernel(
    const int2* __restrict__ recs,
    const int*  __restrict__ cnt,
    const unsigned short* __restrict__ wflat,
    float* __restrict__ out)
{
  const int k   = blockIdx.x & 7;
  const int grp = blockIdx.x >> 3;     // 0..1023, 8 wave-segments each
#pragma unroll
  for (int s = 0; s < 8; ++s) {
    const int wseg = (grp * 8 + s) * NBUCK + k;
    int c = cnt[wseg];                 // uniform across block (broadcast)
    if ((int)threadIdx.x < c) {
      int2 r = recs[(size_t)wseg * SEGCAP + threadIdx.x];
      const unsigned lo = (unsigned)r.x;
      const unsigned sp = lo & 0x3FFFFFu;
      const unsigned kp = lo >> 22;
      float val = __half2float(__ushort_as_half(wflat[sp])) * __int_as_float(r.y);
      if (val != 0.0f) {               // ~78% zero (mask + fp16 underflow)
        unsigned ray = sp / 48u;
        atomicAdd(&out[(size_t)ray * OSTRIDE + 5u + kp], val);
      }
    }
  }
}

// Fallback direct scatter (used only if ws_size can't hold the bins)
__global__ __launch_bounds__(256) void scatter_kernel(
    const float* __restrict__ kp_w,
    const int*   __restrict__ sidx,
    const int*   __restrict__ kidx,
    const unsigned short* __restrict__ wflat,
    float* __restrict__ out)
{
  const int t = blockIdx.x * blockDim.x + threadIdx.x;
  const int4*   s4 = reinterpret_cast<const int4*>(sidx);
  const int4*   k4 = reinterpret_cast<const int4*>(kidx);
  const float4* w4 = reinterpret_cast<const float4*>(kp_w);
  int4 si0 = s4[2 * t], si1 = s4[2 * t + 1];
  const int ss[8] = {si0.x, si0.y, si0.z, si0.w, si1.x, si1.y, si1.z, si1.w};
  unsigned short g[8];
#pragma unroll
  for (int j = 0; j < 8; ++j) g[j] = wflat[ss[j]];
  int4   ki0 = k4[2 * t], ki1 = k4[2 * t + 1];
  float4 w0  = w4[2 * t], w1  = w4[2 * t + 1];
  const int   kk[8] = {ki0.x, ki0.y, ki0.z, ki0.w, ki1.x, ki1.y, ki1.z, ki1.w};
  const float ww[8] = {w0.x, w0.y, w0.z, w0.w, w1.x, w1.y, w1.z, w1.w};
#pragma unroll
  for (int j = 0; j < 8; ++j) {
    float val = __half2float(__ushort_as_half(g[j])) * ww[j];
    if (val != 0.0f) {
      unsigned ray = (unsigned)ss[j] / (unsigned)NP;
      atomicAdd(&out[(size_t)ray * OSTRIDE + 5u + (unsigned)kk[j]], val);
    }
  }
}

__global__ __launch_bounds__(256) void finalize_kernel(
    float* __restrict__ out, const unsigned* __restrict__ red)
{
  const int t   = blockIdx.x * blockDim.x + threadIdx.x;  // NRAYS*NKP threads
  const int ray = t >> 6;
  const int k   = t & 63;
  const size_t ob = (size_t)ray * OSTRIDE;
  float v = out[ob + 5 + k];
  out[ob + 5 + k] = fminf(fmaxf(v, 0.0f), 1.0f);
  if (k == 0) {
    const float gmin = __uint_as_float(red[0]);
    const float gmax = __uint_as_float(red[1]);
    float d = out[ob + 1];
    if (d != d) d = __int_as_float(0x7F800000);  // NaN -> inf
    d = fminf(fmaxf(d, gmin), gmax);
    out[ob + 1] = d;
  }
}

extern "C" void kernel_launch(void* const* d_in, const int* in_sizes, int n_in,
                              void* d_out, int out_size, void* d_ws, size_t ws_size,
                              hipStream_t stream) {
  const float* shape    = (const float*)d_in[0];
  const float* depths   = (const float*)d_in[1];
  const float* channels = (const float*)d_in[2];
  const float* kp_w     = (const float*)d_in[3];
  const int*   kp_sidx  = (const int*)  d_in[4];
  const int*   kp_kidx  = (const int*)  d_in[5];
  const int*   valid    = (const int*)  d_in[6];

  float*          out   = (float*)d_out;
  unsigned*       red   = (unsigned*)d_ws;
  unsigned short* wflat = (unsigned short*)((char*)d_ws + WS_WFLAT_OFF);
  int*            cnt   = (int*) ((char*)d_ws + WS_CNT_OFF);
  int2*           recs  = (int2*)((char*)d_ws + WS_REC_OFF);

  hipMemsetAsync(d_out, 0, (size_t)out_size * sizeof(float), stream);
  init_red<<<1, 1, 0, stream>>>(red);
  composite_kernel<<<NRAYS * 4 / 256, 256, 0, stream>>>(
      shape, depths, channels, valid, out, wflat, red);

  if (ws_size >= WS_NEED) {
    bin_kernel<<<NWAVES / 4, 256, 0, stream>>>(
        kp_sidx, kp_kidx, kp_w, recs, cnt);
    kp_accum_kernel<<<NWAVES, 256, 0, stream>>>(
        recs, cnt, wflat, out);
  } else {
    scatter_kernel<<<NPAIRS / 8 / 256, 256, 0, stream>>>(
        kp_w, kp_sidx, kp_kidx, wflat, out);
  }
  finalize_kernel<<<NRAYS * NKP / 256, 256, 0, stream>>>(out, red);
}

// Round 9
// 310.429 us; speedup vs baseline: 1.3996x; 1.3996x over previous
//
#include <hip/hip_runtime.h>
#include <hip/hip_fp16.h>

#define NRAYS   65536      // B*T*R = 4*2*8192
#define NP      48         // samples per ray
#define NKP     64
#define OSTRIDE 69         // mask(1) + depth(1) + ch(3) + kp(64)
#define NPAIRS  8388608
#define CBLOCKS (NRAYS * 4 / 256)   // composite grid = 1024 blocks

// ws layout (64B-aligned):
//   [0)     red[2]  : float-bits of global depth min/max
//   [64)    bmm     : CBLOCKS float2 per-block {min,max}   (8,192 B)
//   [8320)  wflat   : NRAYS*NP fp16 masked weights         (6,291,456 B)
#define WS_BMM_OFF   64
#define WS_WFLAT_OFF 8320

// 4 lanes per ray; lane `seg` owns samples [12*seg, 12*seg+12).
// Transmittance is a product recurrence; 3 shfls reconstruct the true prefix.
// Depth min/max: per-block LDS reduce -> bmm[block] (NO same-address global
// atomics — round-7 profile showed 8192 same-line atomics serialized the
// whole kernel: 115us at 7% HBM, 3% VALU).
__global__ __launch_bounds__(256) void composite_kernel(
    const float* __restrict__ shape,
    const float* __restrict__ depths,
    const float* __restrict__ channels,
    const int*   __restrict__ valid,
    float* __restrict__ out,
    unsigned short* __restrict__ wflat,
    float2* __restrict__ bmm)
{
  const int gt   = blockIdx.x * blockDim.x + threadIdx.x;
  const int ray  = gt >> 2;          // 64 rays per 256-thread block
  const int seg  = gt & 3;
  const int lane = threadIdx.x & 63;
  const int wid  = threadIdx.x >> 6;

  const float4* s4 = reinterpret_cast<const float4*>(shape  + (size_t)ray * NP + seg * 12);
  const float4* d4 = reinterpret_cast<const float4*>(depths + (size_t)ray * NP + seg * 12);
  const int4*   v4 = reinterpret_cast<const int4*>  (valid  + (size_t)ray * NP + seg * 12);
  const float4* c4 = reinterpret_cast<const float4*>(channels + (size_t)ray * NP * 3 + seg * 36);

  float Tl = 1.0f;
  float wt = 0.0f, wd = 0.0f;
  float c0 = 0.0f, c1 = 0.0f, c2 = 0.0f;
  float wm[12];
  float dmin = __int_as_float(0x7F800000);
  float dmax = 0.0f;

#pragma unroll
  for (int c = 0; c < 3; ++c) {
    float4 s = s4[c];
    float4 d = d4[c];
    int4   v = v4[c];
    float4 ca = c4[c * 3 + 0];
    float4 cb = c4[c * 3 + 1];
    float4 cc = c4[c * 3 + 2];
    float sv[4]  = {s.x, s.y, s.z, s.w};
    float dv[4]  = {d.x, d.y, d.z, d.w};
    int   vv[4]  = {v.x, v.y, v.z, v.w};
    float cf[12] = {ca.x, ca.y, ca.z, ca.w, cb.x, cb.y, cb.z, cb.w,
                    cc.x, cc.y, cc.z, cc.w};
#pragma unroll
    for (int j = 0; j < 4; ++j) {
      float a = 1.0f / (1.0f + expf(-sv[j]));   // sigmoid
      float w = a * Tl;
      Tl = Tl * ((1.0f - a) + 1e-10f);          // reference op order
      wt += w;
      wd += w * dv[j];
      float m = vv[j] ? w : 0.0f;
      wm[c * 4 + j] = m;
      c0 += m * cf[3 * j + 0];
      c1 += m * cf[3 * j + 1];
      c2 += m * cf[3 * j + 2];
      dmin = fminf(dmin, dv[j]);
      dmax = fmaxf(dmax, dv[j]);
    }
  }

  // prefix product over the 4-lane group
  const int base = lane & ~3;
  const float P0 = __shfl(Tl, base + 0, 64);
  const float P1 = __shfl(Tl, base + 1, 64);
  const float P2 = __shfl(Tl, base + 2, 64);
  float Tpre = 1.0f;
  if (seg > 0) Tpre *= P0;
  if (seg > 1) Tpre *= P1;
  if (seg > 2) Tpre *= P2;

  wt *= Tpre; wd *= Tpre; c0 *= Tpre; c1 *= Tpre; c2 *= Tpre;
  wt += __shfl_xor(wt, 1, 64); wt += __shfl_xor(wt, 2, 64);
  wd += __shfl_xor(wd, 1, 64); wd += __shfl_xor(wd, 2, 64);
  c0 += __shfl_xor(c0, 1, 64); c0 += __shfl_xor(c0, 2, 64);
  c1 += __shfl_xor(c1, 1, 64); c1 += __shfl_xor(c1, 2, 64);
  c2 += __shfl_xor(c2, 1, 64); c2 += __shfl_xor(c2, 2, 64);

  ushort4* w4o = reinterpret_cast<ushort4*>(wflat + (size_t)ray * NP + seg * 12);
#pragma unroll
  for (int c = 0; c < 3; ++c) {
    ushort4 h;
    h.x = __half_as_ushort(__float2half(Tpre * wm[c * 4 + 0]));
    h.y = __half_as_ushort(__float2half(Tpre * wm[c * 4 + 1]));
    h.z = __half_as_ushort(__float2half(Tpre * wm[c * 4 + 2]));
    h.w = __half_as_ushort(__float2half(Tpre * wm[c * 4 + 3]));
    w4o[c] = h;
  }

  if (seg == 0) {
    const size_t ob = (size_t)ray * OSTRIDE;
    out[ob + 0] = fminf(fmaxf(wt, 0.0f), 1.0f);
    out[ob + 1] = wd / wt;                        // depth (clipped in finalize)
    out[ob + 2] = fminf(fmaxf(c0, 0.0f), 1.0f);
    out[ob + 3] = fminf(fmaxf(c1, 0.0f), 1.0f);
    out[ob + 4] = fminf(fmaxf(c2, 0.0f), 1.0f);
  }

  // depth min/max: wave butterfly, then block LDS reduce, one plain store
#pragma unroll
  for (int o = 32; o >= 1; o >>= 1) {
    dmin = fminf(dmin, __shfl_xor(dmin, o, 64));
    dmax = fmaxf(dmax, __shfl_xor(dmax, o, 64));
  }
  __shared__ float smn[4], smx[4];
  if (lane == 0) { smn[wid] = dmin; smx[wid] = dmax; }
  __syncthreads();
  if (threadIdx.x == 0) {
    float mn = fminf(fminf(smn[0], smn[1]), fminf(smn[2], smn[3]));
    float mx = fmaxf(fmaxf(smx[0], smx[1]), fmaxf(smx[2], smx[3]));
    bmm[blockIdx.x] = make_float2(mn, mx);
  }
}

// 1024 per-block {min,max} -> red[0..1] (float bits). One block.
__global__ __launch_bounds__(256) void reduce_red(
    const float2* __restrict__ bmm, unsigned* __restrict__ red)
{
  const int lane = threadIdx.x & 63;
  const int wid  = threadIdx.x >> 6;
  float mn = __int_as_float(0x7F800000);
  float mx = 0.0f;
  for (int i = threadIdx.x; i < CBLOCKS; i += 256) {
    float2 v = bmm[i];
    mn = fminf(mn, v.x);
    mx = fmaxf(mx, v.y);
  }
#pragma unroll
  for (int o = 32; o >= 1; o >>= 1) {
    mn = fminf(mn, __shfl_xor(mn, o, 64));
    mx = fmaxf(mx, __shfl_xor(mx, o, 64));
  }
  __shared__ float smn[4], smx[4];
  if (lane == 0) { smn[wid] = mn; smx[wid] = mx; }
  __syncthreads();
  if (threadIdx.x == 0) {
    mn = fminf(fminf(smn[0], smn[1]), fminf(smn[2], smn[3]));
    mx = fmaxf(fmaxf(smx[0], smx[1]), fmaxf(smx[2], smx[3]));
    red[0] = __float_as_uint(mn);
    red[1] = __float_as_uint(mx);
  }
}

// Direct scatter (round-4 measured: 130us, 279MB fetch). 8 pairs/thread,
// all gathers issued before any atomic.
__global__ __launch_bounds__(256) void scatter_kernel(
    const float* __restrict__ kp_w,
    const int*   __restrict__ sidx,
    const int*   __restrict__ kidx,
    const unsigned short* __restrict__ wflat,
    float* __restrict__ out)
{
  const int t = blockIdx.x * blockDim.x + threadIdx.x;
  const int4*   s4 = reinterpret_cast<const int4*>(sidx);
  const int4*   k4 = reinterpret_cast<const int4*>(kidx);
  const float4* w4 = reinterpret_cast<const float4*>(kp_w);
  int4 si0 = s4[2 * t], si1 = s4[2 * t + 1];
  const int ss[8] = {si0.x, si0.y, si0.z, si0.w, si1.x, si1.y, si1.z, si1.w};
  unsigned short g[8];
#pragma unroll
  for (int j = 0; j < 8; ++j) g[j] = wflat[ss[j]];
  int4   ki0 = k4[2 * t], ki1 = k4[2 * t + 1];
  float4 w0  = w4[2 * t], w1  = w4[2 * t + 1];
  const int   kk[8] = {ki0.x, ki0.y, ki0.z, ki0.w, ki1.x, ki1.y, ki1.z, ki1.w};
  const float ww[8] = {w0.x, w0.y, w0.z, w0.w, w1.x, w1.y, w1.z, w1.w};
#pragma unroll
  for (int j = 0; j < 8; ++j) {
    float val = __half2float(__ushort_as_half(g[j])) * ww[j];
    if (val != 0.0f) {                       // ~78% skip (mask + fp16 underflow)
      unsigned ray = (unsigned)ss[j] / (unsigned)NP;
      atomicAdd(&out[(size_t)ray * OSTRIDE + 5u + (unsigned)kk[j]], val);
    }
  }
}

__global__ __launch_bounds__(256) void finalize_kernel(
    float* __restrict__ out, const unsigned* __restrict__ red)
{
  const int t   = blockIdx.x * blockDim.x + threadIdx.x;  // NRAYS*NKP threads
  const int ray = t >> 6;
  const int k   = t & 63;
  const size_t ob = (size_t)ray * OSTRIDE;
  float v = out[ob + 5 + k];
  out[ob + 5 + k] = fminf(fmaxf(v, 0.0f), 1.0f);
  if (k == 0) {
    const float gmin = __uint_as_float(red[0]);
    const float gmax = __uint_as_float(red[1]);
    float d = out[ob + 1];
    if (d != d) d = __int_as_float(0x7F800000);  // NaN -> inf
    d = fminf(fmaxf(d, gmin), gmax);             // clip to global depth range
    out[ob + 1] = d;
  }
}

extern "C" void kernel_launch(void* const* d_in, const int* in_sizes, int n_in,
                              void* d_out, int out_size, void* d_ws, size_t ws_size,
                              hipStream_t stream) {
  const float* shape    = (const float*)d_in[0];
  const float* depths   = (const float*)d_in[1];
  const float* channels = (const float*)d_in[2];
  const float* kp_w     = (const float*)d_in[3];
  const int*   kp_sidx  = (const int*)  d_in[4];
  const int*   kp_kidx  = (const int*)  d_in[5];
  const int*   valid    = (const int*)  d_in[6];

  float*          out   = (float*)d_out;
  unsigned*       red   = (unsigned*)d_ws;
  float2*         bmm   = (float2*)((char*)d_ws + WS_BMM_OFF);
  unsigned short* wflat = (unsigned short*)((char*)d_ws + WS_WFLAT_OFF);

  hipMemsetAsync(d_out, 0, (size_t)out_size * sizeof(float), stream);
  composite_kernel<<<CBLOCKS, 256, 0, stream>>>(
      shape, depths, channels, valid, out, wflat, bmm);
  reduce_red<<<1, 256, 0, stream>>>(bmm, red);
  scatter_kernel<<<NPAIRS / 8 / 256, 256, 0, stream>>>(
      kp_w, kp_sidx, kp_kidx, wflat, out);
  finalize_kernel<<<NRAYS * NKP / 256, 256, 0, stream>>>(out, red);
}

// Round 13
// 299.776 us; speedup vs baseline: 1.4494x; 1.0355x over previous
//
#include <hip/hip_runtime.h>
#include <hip/hip_fp16.h>

#define NRAYS   65536      // B*T*R = 4*2*8192
#define NP      48         // samples per ray
#define NKP     64
#define OSTRIDE 69         // mask(1) + depth(1) + ch(3) + kp(64)
#define NPAIRS  8388608
#define CBLOCKS (NRAYS * 4 / 256)   // composite grid = 1024 blocks

// ws layout (64B-aligned):
//   [0)     red[2]  : float-bits of global depth min/max
//   [64)    bmm     : CBLOCKS float2 per-block {min,max}   (8,192 B)
//   [8320)  wflat   : NRAYS*NP fp16 masked weights         (6,291,456 B)
#define WS_BMM_OFF   64
#define WS_WFLAT_OFF 8320

// --- nontemporal vector loads (streaming data: don't pollute L2) ---------
typedef int   __attribute__((ext_vector_type(4))) i32x4;
typedef float __attribute__((ext_vector_type(4))) f32x4;
__device__ __forceinline__ int4 ntload_i4(const int4* p) {
  i32x4 v = __builtin_nontemporal_load(reinterpret_cast<const i32x4*>(p));
  return make_int4(v.x, v.y, v.z, v.w);
}
__device__ __forceinline__ float4 ntload_f4(const float4* p) {
  f32x4 v = __builtin_nontemporal_load(reinterpret_cast<const f32x4*>(p));
  return make_float4(v.x, v.y, v.z, v.w);
}

// 4 lanes per ray; lane `seg` owns samples [12*seg, 12*seg+12).
// ALL 18 vector loads are issued into registers BEFORE any compute:
// round-7/9 profiles showed VGPR_Count=36 -> only ~4 loads in flight ->
// latency-bound at 7% HBM (573 GB/s). Prefetching trades VGPRs for MLP.
// (BYTE-IDENTICAL to round-9 submission — still unmeasured; do not touch.)
__global__ __launch_bounds__(256) void composite_kernel(
    const float* __restrict__ shape,
    const float* __restrict__ depths,
    const float* __restrict__ channels,
    const int*   __restrict__ valid,
    float* __restrict__ out,
    unsigned short* __restrict__ wflat,
    float2* __restrict__ bmm)
{
  const int gt   = blockIdx.x * blockDim.x + threadIdx.x;
  const int ray  = gt >> 2;          // 64 rays per 256-thread block
  const int seg  = gt & 3;
  const int lane = threadIdx.x & 63;
  const int wid  = threadIdx.x >> 6;

  const float4* s4 = reinterpret_cast<const float4*>(shape  + (size_t)ray * NP + seg * 12);
  const float4* d4 = reinterpret_cast<const float4*>(depths + (size_t)ray * NP + seg * 12);
  const int4*   v4 = reinterpret_cast<const int4*>  (valid  + (size_t)ray * NP + seg * 12);
  const float4* c4 = reinterpret_cast<const float4*>(channels + (size_t)ray * NP * 3 + seg * 36);

  // ---- prefetch everything (18 independent dwordx4 loads in flight) ----
  float4 S[3], D[3], C[9];
  int4   V[3];
#pragma unroll
  for (int c = 0; c < 3; ++c) { S[c] = s4[c]; D[c] = d4[c]; V[c] = v4[c]; }
#pragma unroll
  for (int c = 0; c < 9; ++c) C[c] = c4[c];

  float Tl = 1.0f;
  float wt = 0.0f, wd = 0.0f;
  float c0 = 0.0f, c1 = 0.0f, c2 = 0.0f;
  float wm[12];
  float dmin = __int_as_float(0x7F800000);
  float dmax = 0.0f;

#pragma unroll
  for (int c = 0; c < 3; ++c) {
    float sv[4]  = {S[c].x, S[c].y, S[c].z, S[c].w};
    float dv[4]  = {D[c].x, D[c].y, D[c].z, D[c].w};
    int   vv[4]  = {V[c].x, V[c].y, V[c].z, V[c].w};
    float cf[12] = {C[c*3+0].x, C[c*3+0].y, C[c*3+0].z, C[c*3+0].w,
                    C[c*3+1].x, C[c*3+1].y, C[c*3+1].z, C[c*3+1].w,
                    C[c*3+2].x, C[c*3+2].y, C[c*3+2].z, C[c*3+2].w};
#pragma unroll
    for (int j = 0; j < 4; ++j) {
      float a = 1.0f / (1.0f + expf(-sv[j]));   // sigmoid
      float w = a * Tl;
      Tl = Tl * ((1.0f - a) + 1e-10f);          // reference op order
      wt += w;
      wd += w * dv[j];
      float m = vv[j] ? w : 0.0f;
      wm[c * 4 + j] = m;
      c0 += m * cf[3 * j + 0];
      c1 += m * cf[3 * j + 1];
      c2 += m * cf[3 * j + 2];
      dmin = fminf(dmin, dv[j]);
      dmax = fmaxf(dmax, dv[j]);
    }
  }

  // prefix product over the 4-lane group
  const int base = lane & ~3;
  const float P0 = __shfl(Tl, base + 0, 64);
  const float P1 = __shfl(Tl, base + 1, 64);
  const float P2 = __shfl(Tl, base + 2, 64);
  float Tpre = 1.0f;
  if (seg > 0) Tpre *= P0;
  if (seg > 1) Tpre *= P1;
  if (seg > 2) Tpre *= P2;

  wt *= Tpre; wd *= Tpre; c0 *= Tpre; c1 *= Tpre; c2 *= Tpre;
  wt += __shfl_xor(wt, 1, 64); wt += __shfl_xor(wt, 2, 64);
  wd += __shfl_xor(wd, 1, 64); wd += __shfl_xor(wd, 2, 64);
  c0 += __shfl_xor(c0, 1, 64); c0 += __shfl_xor(c0, 2, 64);
  c1 += __shfl_xor(c1, 1, 64); c1 += __shfl_xor(c1, 2, 64);
  c2 += __shfl_xor(c2, 1, 64); c2 += __shfl_xor(c2, 2, 64);

  ushort4* w4o = reinterpret_cast<ushort4*>(wflat + (size_t)ray * NP + seg * 12);
#pragma unroll
  for (int c = 0; c < 3; ++c) {
    ushort4 h;
    h.x = __half_as_ushort(__float2half(Tpre * wm[c * 4 + 0]));
    h.y = __half_as_ushort(__float2half(Tpre * wm[c * 4 + 1]));
    h.z = __half_as_ushort(__float2half(Tpre * wm[c * 4 + 2]));
    h.w = __half_as_ushort(__float2half(Tpre * wm[c * 4 + 3]));
    w4o[c] = h;
  }

  if (seg == 0) {
    const size_t ob = (size_t)ray * OSTRIDE;
    out[ob + 0] = fminf(fmaxf(wt, 0.0f), 1.0f);
    out[ob + 1] = wd / wt;                        // depth (clipped in finalize)
    out[ob + 2] = fminf(fmaxf(c0, 0.0f), 1.0f);
    out[ob + 3] = fminf(fmaxf(c1, 0.0f), 1.0f);
    out[ob + 4] = fminf(fmaxf(c2, 0.0f), 1.0f);
  }

  // depth min/max: wave butterfly, then block LDS reduce, one plain store
#pragma unroll
  for (int o = 32; o >= 1; o >>= 1) {
    dmin = fminf(dmin, __shfl_xor(dmin, o, 64));
    dmax = fmaxf(dmax, __shfl_xor(dmax, o, 64));
  }
  __shared__ float smn[4], smx[4];
  if (lane == 0) { smn[wid] = dmin; smx[wid] = dmax; }
  __syncthreads();
  if (threadIdx.x == 0) {
    float mn = fminf(fminf(smn[0], smn[1]), fminf(smn[2], smn[3]));
    float mx = fmaxf(fmaxf(smx[0], smx[1]), fmaxf(smx[2], smx[3]));
    bmm[blockIdx.x] = make_float2(mn, mx);
  }
}

// 1024 per-block {min,max} -> red[0..1] (float bits). One block.
__global__ __launch_bounds__(256) void reduce_red(
    const float2* __restrict__ bmm, unsigned* __restrict__ red)
{
  const int lane = threadIdx.x & 63;
  const int wid  = threadIdx.x >> 6;
  float mn = __int_as_float(0x7F800000);
  float mx = 0.0f;
  for (int i = threadIdx.x; i < CBLOCKS; i += 256) {
    float2 v = bmm[i];
    mn = fminf(mn, v.x);
    mx = fmaxf(mx, v.y);
  }
#pragma unroll
  for (int o = 32; o >= 1; o >>= 1) {
    mn = fminf(mn, __shfl_xor(mn, o, 64));
    mx = fmaxf(mx, __shfl_xor(mx, o, 64));
  }
  __shared__ float smn[4], smx[4];
  if (lane == 0) { smn[wid] = mn; smx[wid] = mx; }
  __syncthreads();
  if (threadIdx.x == 0) {
    mn = fminf(fminf(smn[0], smn[1]), fminf(smn[2], smn[3]));
    mx = fmaxf(fmaxf(smx[0], smx[1]), fmaxf(smx[2], smx[3]));
    red[0] = __float_as_uint(mn);
    red[1] = __float_as_uint(mx);
  }
}

// Direct scatter (measured 3x: ~128us, 280MB fetch, wflat hit ~63%).
// NEW: pair streams (sidx/kidx/kp_w, 96MB touched once) loaded NONTEMPORAL
// so they stop evicting the 6.3MB wflat gather table from per-XCD L2.
// Gather loads stay cached. 8 pairs/thread, gathers issued before atomics.
__global__ __launch_bounds__(256) void scatter_kernel(
    const float* __restrict__ kp_w,
    const int*   __restrict__ sidx,
    const int*   __restrict__ kidx,
    const unsigned short* __restrict__ wflat,
    float* __restrict__ out)
{
  const int t = blockIdx.x * blockDim.x + threadIdx.x;
  const int4*   s4 = reinterpret_cast<const int4*>(sidx);
  const int4*   k4 = reinterpret_cast<const int4*>(kidx);
  const float4* w4 = reinterpret_cast<const float4*>(kp_w);
  int4 si0 = ntload_i4(&s4[2 * t]), si1 = ntload_i4(&s4[2 * t + 1]);
  const int ss[8] = {si0.x, si0.y, si0.z, si0.w, si1.x, si1.y, si1.z, si1.w};
  unsigned short g[8];
#pragma unroll
  for (int j = 0; j < 8; ++j) g[j] = wflat[ss[j]];
  int4   ki0 = ntload_i4(&k4[2 * t]), ki1 = ntload_i4(&k4[2 * t + 1]);
  float4 w0  = ntload_f4(&w4[2 * t]), w1  = ntload_f4(&w4[2 * t + 1]);
  const int   kk[8] = {ki0.x, ki0.y, ki0.z, ki0.w, ki1.x, ki1.y, ki1.z, ki1.w};
  const float ww[8] = {w0.x, w0.y, w0.z, w0.w, w1.x, w1.y, w1.z, w1.w};
#pragma unroll
  for (int j = 0; j < 8; ++j) {
    float val = __half2float(__ushort_as_half(g[j])) * ww[j];
    if (val != 0.0f) {                       // ~78% skip (mask + fp16 underflow)
      unsigned ray = (unsigned)ss[j] / (unsigned)NP;
      atomicAdd(&out[(size_t)ray * OSTRIDE + 5u + (unsigned)kk[j]], val);
    }
  }
}

__global__ __launch_bounds__(256) void finalize_kernel(
    float* __restrict__ out, const unsigned* __restrict__ red)
{
  const int t   = blockIdx.x * blockDim.x + threadIdx.x;  // NRAYS*NKP threads
  const int ray = t >> 6;
  const int k   = t & 63;
  const size_t ob = (size_t)ray * OSTRIDE;
  float v = out[ob + 5 + k];
  out[ob + 5 + k] = fminf(fmaxf(v, 0.0f), 1.0f);
  if (k == 0) {
    const float gmin = __uint_as_float(red[0]);
    const float gmax = __uint_as_float(red[1]);
    float d = out[ob + 1];
    if (d != d) d = __int_as_float(0x7F800000);  // NaN -> inf
    d = fminf(fmaxf(d, gmin), gmax);             // clip to global depth range
    out[ob + 1] = d;
  }
}

extern "C" void kernel_launch(void* const* d_in, const int* in_sizes, int n_in,
                              void* d_out, int out_size, void* d_ws, size_t ws_size,
                              hipStream_t stream) {
  const float* shape    = (const float*)d_in[0];
  const float* depths   = (const float*)d_in[1];
  const float* channels = (const float*)d_in[2];
  const float* kp_w     = (const float*)d_in[3];
  const int*   kp_sidx  = (const int*)  d_in[4];
  const int*   kp_kidx  = (const int*)  d_in[5];
  const int*   valid    = (const int*)  d_in[6];

  float*          out   = (float*)d_out;
  unsigned*       red   = (unsigned*)d_ws;
  float2*         bmm   = (float2*)((char*)d_ws + WS_BMM_OFF);
  unsigned short* wflat = (unsigned short*)((char*)d_ws + WS_WFLAT_OFF);

  hipMemsetAsync(d_out, 0, (size_t)out_size * sizeof(float), stream);
  composite_kernel<<<CBLOCKS, 256, 0, stream>>>(
      shape, depths, channels, valid, out, wflat, bmm);
  reduce_red<<<1, 256, 0, stream>>>(bmm, red);
  scatter_kernel<<<NPAIRS / 8 / 256, 256, 0, stream>>>(
      kp_w, kp_sidx, kp_kidx, wflat, out);
  finalize_kernel<<<NRAYS * NKP / 256, 256, 0, stream>>>(out, red);
}